// Round 1
// baseline (286.024 us; speedup 1.0000x reference)
//
#include <hip/hip_runtime.h>

#define NF   256   // IN_F
#define HD   256   // H*D
#define NH   4
#define DH   64
#define WINS 128   // WIN
#define HALFW 64
#define TOPK 32

// ---------------- Q/K projection: X[n,256] @ W[256,256] + b ----------------
__global__ __launch_bounds__(256) void qk_gemm_kernel(
    const float* __restrict__ X,
    const float* __restrict__ W,
    const float* __restrict__ b,
    float* __restrict__ Out, int n)
{
    __shared__ float feat[32][NF];
    const int rowBase = blockIdx.x * 32;
    const int t = threadIdx.x;

    for (int idx = t; idx < 32 * NF; idx += 256) {
        int r = idx >> 8, c = idx & 255;
        feat[r][c] = X[(size_t)(rowBase + r) * NF + c];
    }
    __syncthreads();

    float acc[32];
#pragma unroll
    for (int r = 0; r < 32; ++r) acc[r] = 0.f;

    for (int k = 0; k < NF; ++k) {
        float w = W[(size_t)k * HD + t];
#pragma unroll
        for (int r = 0; r < 32; ++r) acc[r] += feat[r][k] * w;
    }
    float bias = b[t];
#pragma unroll
    for (int r = 0; r < 32; ++r)
        Out[(size_t)(rowBase + r) * HD + t] = acc[r] + bias;
}

// ------------- per-node windowed attention + top-32 + row write -------------
__global__ __launch_bounds__(128) void attn_topk_kernel(
    const float* __restrict__ Q,
    const float* __restrict__ K,
    const int* __restrict__ nnpg, int n_graphs,
    const int* __restrict__ nrel,
    float* __restrict__ out, int n)
{
    const int i = blockIdx.x;
    const int m = threadIdx.x;

    __shared__ float  qs[HD];
    __shared__ float4 red[WINS];
    __shared__ float  attnv[WINS];
    __shared__ float  slotval[WINS];

    // segment bounds (generic: tile(nnpg, R) -> cumsum -> searchsorted right)
    int R = nrel[0];
    int total = n_graphs * R;
    int seg_start = 0, seg_end = n;
    int cum = 0;
    for (int e = 0; e < total; ++e) {
        int sz = nnpg[e % n_graphs];
        int nc = cum + sz;
        if (i < nc) { seg_start = cum; seg_end = nc; break; }
        cum = nc;
    }
    const int start = max(seg_start, i - HALFW);
    const int end   = min(seg_end,   i + HALFW);
    const int win   = end - start;          // valid slots: m in [0, win)

    qs[m]       = Q[(size_t)i * HD + m];
    qs[m + 128] = Q[(size_t)i * HD + m + 128];
    __syncthreads();

    const bool valid = (m < win);
    float4 s = make_float4(0.f, 0.f, 0.f, 0.f);   // padded slots: score exactly 0
    if (valid) {
        const float4* krow = (const float4*)(K + (size_t)(start + m) * HD);
        float sh[NH];
#pragma unroll
        for (int h = 0; h < NH; ++h) {
            const float4* kh = krow + h * 16;
            const float*  qh = qs + h * DH;
            float a = 0.f;
#pragma unroll
            for (int d = 0; d < 16; ++d) {
                float4 kv = kh[d];
                a += qh[4*d+0]*kv.x + qh[4*d+1]*kv.y + qh[4*d+2]*kv.z + qh[4*d+3]*kv.w;
            }
            sh[h] = a * 0.25f;   // /sqrt(64)/tau = /8/0.5
        }
        s = make_float4(sh[0], sh[1], sh[2], sh[3]);
    }

    // per-head max over the full 128-slot window (padded slots contribute 0)
    red[m] = s;
    __syncthreads();
    for (int off = 64; off > 0; off >>= 1) {
        if (m < off) {
            float4 a = red[m], bb = red[m + off];
            a.x = fmaxf(a.x, bb.x); a.y = fmaxf(a.y, bb.y);
            a.z = fmaxf(a.z, bb.z); a.w = fmaxf(a.w, bb.w);
            red[m] = a;
        }
        __syncthreads();
    }
    float4 M = red[0];
    __syncthreads();    // everyone read red[0] before reuse

    float4 e;
    e.x = expf(s.x - M.x); e.y = expf(s.y - M.y);
    e.z = expf(s.z - M.z); e.w = expf(s.w - M.w);
    red[m] = e;
    __syncthreads();
    for (int off = 64; off > 0; off >>= 1) {
        if (m < off) {
            float4 a = red[m], bb = red[m + off];
            a.x += bb.x; a.y += bb.y; a.z += bb.z; a.w += bb.w;
            red[m] = a;
        }
        __syncthreads();
    }
    float4 Dn = red[0];

    float a_mean = 0.25f * (e.x / Dn.x + e.y / Dn.y + e.z / Dn.z + e.w / Dn.w);
    attnv[m] = valid ? a_mean : -1.0f;
    __syncthreads();

    // stable top-32 via rank counting (lower index wins ties, like lax.top_k)
    float v = attnv[m];
    int cnt = 0;
#pragma unroll 8
    for (int j = 0; j < WINS; ++j) {
        float aj = attnv[j];
        cnt += (aj > v) || (aj == v && j < m);
    }
    bool sel = valid && (cnt < TOPK);
    slotval[m] = sel ? 1.0f : 0.0f;
    __syncthreads();

    // write full output row: zeros + ones, fused single pass, float4 stores
    float4* orow = (float4*)(out + (size_t)i * n);
    int n4 = n >> 2;
    for (int c4 = m; c4 < n4; c4 += 128) {
        int c = c4 << 2;
        float4 v4 = make_float4(0.f, 0.f, 0.f, 0.f);
        if (c + 3 >= start && c < end) {
            int o = c - start;
            if (o   >= 0 && o   < WINS) v4.x = slotval[o];
            if (o+1 >= 0 && o+1 < WINS) v4.y = slotval[o+1];
            if (o+2 >= 0 && o+2 < WINS) v4.z = slotval[o+2];
            if (o+3 >= 0 && o+3 < WINS) v4.w = slotval[o+3];
        }
        orow[c4] = v4;
    }
}

extern "C" void kernel_launch(void* const* d_in, const int* in_sizes, int n_in,
                              void* d_out, int out_size, void* d_ws, size_t ws_size,
                              hipStream_t stream)
{
    const float* X  = (const float*)d_in[0];
    const float* Wq = (const float*)d_in[1];
    const float* bq = (const float*)d_in[2];
    const float* Wk = (const float*)d_in[3];
    const float* bk = (const float*)d_in[4];
    const int* nnpg = (const int*)d_in[5];
    const int* nrel = (const int*)d_in[6];

    const int n = in_sizes[0] / NF;
    const int n_graphs = in_sizes[5];

    float* Qb = (float*)d_ws;
    float* Kb = Qb + (size_t)n * HD;
    float* out = (float*)d_out;

    dim3 g1(n / 32), b1(256);
    qk_gemm_kernel<<<g1, b1, 0, stream>>>(X, Wq, bq, Qb, n);
    qk_gemm_kernel<<<g1, b1, 0, stream>>>(X, Wk, bk, Kb, n);
    attn_topk_kernel<<<n, 128, 0, stream>>>(Qb, Kb, nnpg, n_graphs, nrel, out, n);
}

// Round 2
// 237.229 us; speedup vs baseline: 1.2057x; 1.2057x over previous
//
#include <hip/hip_runtime.h>

#define NF   256   // IN_F
#define HD   256   // H*D
#define NH   4
#define DH   64
#define WINS 128   // WIN
#define HALFW 64
#define TOPK 32
#define GR   16    // rows per gemm block

// ------------- fused Q/K projection: X[n,256] @ W[256,256] + b -------------
// grid (n/GR, 2); blockIdx.y==0 -> Q, ==1 -> K. 256 threads: thread t owns
// output column t for GR rows.
__global__ __launch_bounds__(256) void qk_gemm_kernel(
    const float* __restrict__ X,
    const float* __restrict__ Wq, const float* __restrict__ bq,
    const float* __restrict__ Wk, const float* __restrict__ bk,
    float* __restrict__ Qb, float* __restrict__ Kb, int n)
{
    const float* W   = blockIdx.y ? Wk : Wq;
    const float* bia = blockIdx.y ? bk : bq;
    float*       Out = blockIdx.y ? Kb : Qb;

    __shared__ float feat[GR][NF];
    const int rowBase = blockIdx.x * GR;
    const int t = threadIdx.x;

    for (int idx = t; idx < GR * NF; idx += 256) {
        int r = idx >> 8, c = idx & 255;
        feat[r][c] = X[(size_t)(rowBase + r) * NF + c];
    }
    __syncthreads();

    float acc[GR];
#pragma unroll
    for (int r = 0; r < GR; ++r) acc[r] = 0.f;

    for (int k = 0; k < NF; k += 4) {
        float w0 = W[(k + 0) * HD + t];
        float w1 = W[(k + 1) * HD + t];
        float w2 = W[(k + 2) * HD + t];
        float w3 = W[(k + 3) * HD + t];
#pragma unroll
        for (int r = 0; r < GR; ++r) {
            float4 f = *(const float4*)&feat[r][k];
            acc[r] += f.x * w0 + f.y * w1 + f.z * w2 + f.w * w3;
        }
    }
    float bias = bia[t];
#pragma unroll
    for (int r = 0; r < GR; ++r)
        Out[(size_t)(rowBase + r) * HD + t] = acc[r] + bias;
}

// ---------------------- streaming zero-fill of output ----------------------
__global__ __launch_bounds__(256) void fill_zero_kernel(float4* __restrict__ p, int n4)
{
    int idx = blockIdx.x * 256 + threadIdx.x;
    int stride = gridDim.x * 256;
    float4 z = make_float4(0.f, 0.f, 0.f, 0.f);
    for (int c = idx; c < n4; c += stride) p[c] = z;
}

// ---- per-node windowed attention + top-32; scatter 1.0s into zeroed out ----
// one block (512 threads) per node i. thread t: slot s = t>>2, head h = t&3.
// K loads are contiguous 256B per lane -> fully coalesced 1KB per wave instr.
__global__ __launch_bounds__(512) void attn_topk_kernel(
    const float* __restrict__ Q,
    const float* __restrict__ K,
    const int* __restrict__ nnpg, int n_graphs,
    const int* __restrict__ nrel,
    float* __restrict__ out, int n)
{
    const int i = blockIdx.x;
    const int t = threadIdx.x;
    const int s = t >> 2;
    const int h = t & 3;

    __shared__ float sc[NH][WINS];   // scores per head (0 for padded slots)
    __shared__ float pr[NH][WINS];   // per-head softmax probs
    __shared__ float attnv[WINS];

    // segment bounds: tile(nnpg, R) -> cumsum -> searchsorted(right)
    int R = nrel[0];
    int total = n_graphs * R;
    int seg_start = 0, seg_end = n;
    int cum = 0;
    for (int e = 0; e < total; ++e) {
        int sz = nnpg[e % n_graphs];
        int nc = cum + sz;
        if (i < nc) { seg_start = cum; seg_end = nc; break; }
        cum = nc;
    }
    const int start = max(seg_start, i - HALFW);
    const int end   = min(seg_end,   i + HALFW);
    const int win   = end - start;           // >= 64 always (segments >= 128)

    // ---- scores: 4 lanes per slot, each lane one head (contiguous 256B) ----
    float acc = 0.f;
    if (s < win) {
        const float4* kp = (const float4*)(K + (size_t)(start + s) * HD + h * DH);
        const float4* qp = (const float4*)(Q + (size_t)i * HD + h * DH);
#pragma unroll
        for (int j = 0; j < 16; ++j) {
            float4 kv = kp[j];
            float4 qv = qp[j];
            acc += qv.x * kv.x + qv.y * kv.y + qv.z * kv.z + qv.w * kv.w;
        }
        acc *= 0.25f;   // /sqrt(64)/tau
    }
    sc[h][s] = acc;     // padded slots: exactly 0, included in softmax (ref behavior)
    __syncthreads();

    // ---- per-head softmax via wave shuffles: wave w handles head w ----
    if (t < 256) {
        int hh = t >> 6, l = t & 63;
        float v0 = sc[hh][l], v1 = sc[hh][l + 64];
        float mx = fmaxf(v0, v1);
#pragma unroll
        for (int off = 32; off > 0; off >>= 1) mx = fmaxf(mx, __shfl_xor(mx, off));
        float e0 = expf(v0 - mx), e1 = expf(v1 - mx);
        float sm = e0 + e1;
#pragma unroll
        for (int off = 32; off > 0; off >>= 1) sm += __shfl_xor(sm, off);
        pr[hh][l]      = e0 / sm;
        pr[hh][l + 64] = e1 / sm;
    }
    __syncthreads();

    // ---- mean over heads, mask invalid, stable top-32 rank count ----
    if (t < WINS) {
        float a = 0.25f * (pr[0][t] + pr[1][t] + pr[2][t] + pr[3][t]);
        attnv[t] = (t < win) ? a : -1.0f;   // invalid slots never in top-k
    }
    __syncthreads();

    if (t < WINS) {
        float v = attnv[t];
        int cnt = 0;
#pragma unroll 8
        for (int j = 0; j < WINS; ++j) {
            float aj = attnv[j];
            cnt += (aj > v) || (aj == v && j < t);
        }
        if (t < win && cnt < TOPK)
            out[(size_t)i * n + start + t] = 1.0f;
    }
}

extern "C" void kernel_launch(void* const* d_in, const int* in_sizes, int n_in,
                              void* d_out, int out_size, void* d_ws, size_t ws_size,
                              hipStream_t stream)
{
    const float* X  = (const float*)d_in[0];
    const float* Wq = (const float*)d_in[1];
    const float* bq = (const float*)d_in[2];
    const float* Wk = (const float*)d_in[3];
    const float* bk = (const float*)d_in[4];
    const int* nnpg = (const int*)d_in[5];
    const int* nrel = (const int*)d_in[6];

    const int n = in_sizes[0] / NF;
    const int n_graphs = in_sizes[5];

    float* Qb = (float*)d_ws;
    float* Kb = Qb + (size_t)n * HD;
    float* out = (float*)d_out;

    dim3 gg(n / GR, 2);
    qk_gemm_kernel<<<gg, 256, 0, stream>>>(X, Wq, bq, Wk, bk, Qb, Kb, n);

    int n4 = out_size >> 2;
    fill_zero_kernel<<<4096, 256, 0, stream>>>((float4*)out, n4);

    attn_topk_kernel<<<n, 512, 0, stream>>>(Qb, Kb, nnpg, n_graphs, nrel, out, n);
}

// Round 3
// 157.103 us; speedup vs baseline: 1.8206x; 1.5100x over previous
//
#include <hip/hip_runtime.h>

#define NF   256   // IN_F
#define HD   256   // H*D
#define NH   4
#define DH   64
#define WINS 128   // WIN
#define HALFW 64
#define TOPK 32
#define GR   8     // rows per gemm block

// ------------- fused Q/K projection: X[n,256] @ W[256,256] + b -------------
// 512 threads: t<256 -> Q column t, t>=256 -> K column t-256. X reads are
// block-uniform (scalarize to s_load); W reads coalesced per wave. No LDS.
__global__ __launch_bounds__(512) void qk_gemm_kernel(
    const float* __restrict__ X,
    const float* __restrict__ Wq, const float* __restrict__ bq,
    const float* __restrict__ Wk, const float* __restrict__ bk,
    float* __restrict__ Qb, float* __restrict__ Kb, int n)
{
    const int t   = threadIdx.x;
    const int col = t & 255;
    const bool isK = (t >= 256);
    const float* W   = isK ? Wk : Wq;
    const float* bia = isK ? bk : bq;
    float*       Out = isK ? Kb : Qb;

    const int rowBase = blockIdx.x * GR;
    const float* Xb = X + (size_t)rowBase * NF;

    float acc[GR];
#pragma unroll
    for (int r = 0; r < GR; ++r) acc[r] = 0.f;

    for (int k = 0; k < NF; k += 4) {
        float w0 = W[(size_t)(k + 0) * HD + col];
        float w1 = W[(size_t)(k + 1) * HD + col];
        float w2 = W[(size_t)(k + 2) * HD + col];
        float w3 = W[(size_t)(k + 3) * HD + col];
#pragma unroll
        for (int r = 0; r < GR; ++r) {
            float4 f = *(const float4*)(Xb + r * NF + k);   // block-uniform
            acc[r] += f.x * w0 + f.y * w1 + f.z * w2 + f.w * w3;
        }
    }
    float bias = bia[col];
#pragma unroll
    for (int r = 0; r < GR; ++r)
        Out[(size_t)(rowBase + r) * HD + col] = acc[r] + bias;
}

// ---- per-node windowed attention + top-32 + fused full-row write ----
// 256 threads (4 waves) per node. One wave loads one full 1KB K-row per step
// (lane l -> float4 at l*16: fully coalesced, 16 lines/instr). Per-head dots
// via 16-lane shfl_xor groups (head = lane>>4).
__global__ __launch_bounds__(256) void attn_topk_kernel(
    const float* __restrict__ Q,
    const float* __restrict__ K,
    const int* __restrict__ nnpg, int n_graphs,
    const int* __restrict__ nrel,
    float* __restrict__ out, int n)
{
    const int i    = blockIdx.x;
    const int t    = threadIdx.x;
    const int wave = t >> 6;
    const int lane = t & 63;

    __shared__ float sc[NH][WINS];     // per-head scores (0 for padded slots)
    __shared__ float pr[NH][WINS];     // per-head softmax probs
    __shared__ float attnv[WINS];
    __shared__ float slotval[WINS];

    // segment bounds: tile(nnpg, R) -> cumsum -> searchsorted(right)
    int R = nrel[0];
    int total = n_graphs * R;
    int seg_start = 0, seg_end = n;
    int cum = 0;
    for (int e = 0; e < total; ++e) {
        int sz = nnpg[e % n_graphs];
        int nc = cum + sz;
        if (i < nc) { seg_start = cum; seg_end = nc; break; }
        cum = nc;
    }
    const int start = max(seg_start, i - HALFW);
    const int end   = min(seg_end,   i + HALFW);
    const int win   = end - start;            // >= 64 (segments >= 128 nodes)

    // lane's Q chunk: dims [4*lane, 4*lane+4), head = lane>>4
    const float4 q4 = *(const float4*)(Q + (size_t)i * HD + lane * 4);

    // ---- scores: wave w handles rows {w + 4j} ----
#pragma unroll 4
    for (int j = 0; j < 32; ++j) {
        int row = wave + 4 * j;               // 0..127
        float v = 0.f;
        if (row < win) {
            float4 k4 = *(const float4*)(K + (size_t)(start + row) * HD + lane * 4);
            v = q4.x * k4.x + q4.y * k4.y + q4.z * k4.z + q4.w * k4.w;
        }
        // sum over the 16-lane group = this head's 64 dims
        v += __shfl_xor(v, 1);
        v += __shfl_xor(v, 2);
        v += __shfl_xor(v, 4);
        v += __shfl_xor(v, 8);
        if ((lane & 15) == 0)
            sc[lane >> 4][row] = v * 0.25f;   // /sqrt(64)/tau; padded rows -> 0
    }
    __syncthreads();

    // ---- per-head softmax over full 128-slot window: wave w = head w ----
    {
        float v0 = sc[wave][lane], v1 = sc[wave][lane + 64];
        float mx = fmaxf(v0, v1);
#pragma unroll
        for (int off = 32; off > 0; off >>= 1) mx = fmaxf(mx, __shfl_xor(mx, off));
        float e0 = expf(v0 - mx), e1 = expf(v1 - mx);
        float sm = e0 + e1;
#pragma unroll
        for (int off = 32; off > 0; off >>= 1) sm += __shfl_xor(sm, off);
        pr[wave][lane]      = e0 / sm;
        pr[wave][lane + 64] = e1 / sm;
    }
    __syncthreads();

    // ---- mean over heads; invalid slots excluded from top-k ----
    if (t < WINS) {
        float a = 0.25f * (pr[0][t] + pr[1][t] + pr[2][t] + pr[3][t]);
        attnv[t] = (t < win) ? a : -1.0f;
    }
    __syncthreads();

    // ---- stable top-32 rank count (lower index wins ties, like lax.top_k) ----
    if (t < WINS) {
        float v = attnv[t];
        int cnt = 0;
#pragma unroll
        for (int j4 = 0; j4 < WINS / 4; ++j4) {
            float4 a4 = *(const float4*)&attnv[j4 * 4];
            int jb = j4 * 4;
            cnt += (a4.x > v) || (a4.x == v && (jb + 0) < t);
            cnt += (a4.y > v) || (a4.y == v && (jb + 1) < t);
            cnt += (a4.z > v) || (a4.z == v && (jb + 2) < t);
            cnt += (a4.w > v) || (a4.w == v && (jb + 3) < t);
        }
        slotval[t] = (t < win && cnt < TOPK) ? 1.0f : 0.0f;
    }
    __syncthreads();

    // ---- fused full-row write: zeros + window values, float4 stores ----
    float4* orow = (float4*)(out + (size_t)i * n);
    const int n4 = n >> 2;
    for (int c4 = t; c4 < n4; c4 += 256) {
        int c = c4 << 2;
        float4 v4 = make_float4(0.f, 0.f, 0.f, 0.f);
        if (c + 3 >= start && c < end) {
            int o = c - start;
            if (o     >= 0 && o     < WINS) v4.x = slotval[o];
            if (o + 1 >= 0 && o + 1 < WINS) v4.y = slotval[o + 1];
            if (o + 2 >= 0 && o + 2 < WINS) v4.z = slotval[o + 2];
            if (o + 3 >= 0 && o + 3 < WINS) v4.w = slotval[o + 3];
        }
        orow[c4] = v4;
    }
}

extern "C" void kernel_launch(void* const* d_in, const int* in_sizes, int n_in,
                              void* d_out, int out_size, void* d_ws, size_t ws_size,
                              hipStream_t stream)
{
    const float* X  = (const float*)d_in[0];
    const float* Wq = (const float*)d_in[1];
    const float* bq = (const float*)d_in[2];
    const float* Wk = (const float*)d_in[3];
    const float* bk = (const float*)d_in[4];
    const int* nnpg = (const int*)d_in[5];
    const int* nrel = (const int*)d_in[6];

    const int n = in_sizes[0] / NF;
    const int n_graphs = in_sizes[5];

    float* Qb = (float*)d_ws;
    float* Kb = Qb + (size_t)n * HD;
    float* out = (float*)d_out;

    qk_gemm_kernel<<<n / GR, 512, 0, stream>>>(X, Wq, bq, Wk, bk, Qb, Kb, n);
    attn_topk_kernel<<<n, 256, 0, stream>>>(Qb, Kb, nnpg, n_graphs, nrel, out, n);
}